// Round 1
// baseline (260.240 us; speedup 1.0000x reference)
//
#include <hip/hip_runtime.h>

// LRU linear scan: h_t = a*h_{t-1} + b*x_t, output full sequence [B,T,D] fp32.
// a = exp(-exp(W)), b = sqrt(1 - (a-1)^2), per channel d.
// 3-phase chunked scan over T: chunk-ends -> carries -> full rescan+write.

#define BB 16
#define TT 4096
#define DD 512
#define KK 64          // chunks along T
#define LL (TT / KK)   // 64 steps per chunk
#define D4 (DD / 4)    // 128 float4 lanes across D

__device__ __forceinline__ void coeffs(const float* __restrict__ W, int d,
                                       float& a0, float& a1, float& a2, float& a3,
                                       float& b0, float& b1, float& b2, float& b3) {
    float w;
    w = expf(-expf(W[d + 0])) - 1.0f; a0 = 1.0f + w; b0 = sqrtf(1.0f - w * w);
    w = expf(-expf(W[d + 1])) - 1.0f; a1 = 1.0f + w; b1 = sqrtf(1.0f - w * w);
    w = expf(-expf(W[d + 2])) - 1.0f; a2 = 1.0f + w; b2 = sqrtf(1.0f - w * w);
    w = expf(-expf(W[d + 3])) - 1.0f; a3 = 1.0f + w; b3 = sqrtf(1.0f - w * w);
}

// Phase 1: per (b, k, d4) scan chunk from h=0, write chunk-end E[b,k,d4].
__global__ __launch_bounds__(D4) void lru_phase1(const float4* __restrict__ x,
                                                 const float* __restrict__ W,
                                                 float4* __restrict__ E) {
    const int d4 = threadIdx.x;     // 0..127
    const int k  = blockIdx.x;      // 0..KK-1
    const int b  = blockIdx.y;      // 0..BB-1
    const int d  = d4 * 4;

    float a0, a1, a2, a3, b0, b1, b2, b3;
    coeffs(W, d, a0, a1, a2, a3, b0, b1, b2, b3);

    const float4* xp = x + ((size_t)b * TT + (size_t)k * LL) * D4 + d4;
    float h0 = 0.f, h1 = 0.f, h2 = 0.f, h3 = 0.f;
#pragma unroll 8
    for (int i = 0; i < LL; ++i) {
        float4 v = xp[(size_t)i * D4];
        h0 = a0 * h0 + b0 * v.x;
        h1 = a1 * h1 + b1 * v.y;
        h2 = a2 * h2 + b2 * v.z;
        h3 = a3 * h3 + b3 * v.w;
    }
    E[((size_t)b * KK + k) * D4 + d4] = make_float4(h0, h1, h2, h3);
}

// Phase 2: in-place E -> carries. carry into chunk k is C_k; C_0 = 0,
// C_{k} = aL * C_{k-1} + E_{k-1}, aL = a^LL.
__global__ __launch_bounds__(D4) void lru_phase2(const float* __restrict__ W,
                                                 float4* __restrict__ E) {
    const int d4 = threadIdx.x;
    const int b  = blockIdx.x;
    const int d  = d4 * 4;

    float a0, a1, a2, a3, b0, b1, b2, b3;
    coeffs(W, d, a0, a1, a2, a3, b0, b1, b2, b3);

    // aL = a^64 via 6 squarings
    float aL0 = a0, aL1 = a1, aL2 = a2, aL3 = a3;
#pragma unroll
    for (int s = 0; s < 6; ++s) { aL0 *= aL0; aL1 *= aL1; aL2 *= aL2; aL3 *= aL3; }

    float c0 = 0.f, c1 = 0.f, c2 = 0.f, c3 = 0.f;
    for (int k = 0; k < KK; ++k) {
        size_t idx = ((size_t)b * KK + k) * D4 + d4;
        float4 e = E[idx];
        E[idx] = make_float4(c0, c1, c2, c3);
        c0 = aL0 * c0 + e.x;
        c1 = aL1 * c1 + e.y;
        c2 = aL2 * c2 + e.z;
        c3 = aL3 * c3 + e.w;
    }
}

// Phase 3: rescan each chunk starting from its carry, write full output.
__global__ __launch_bounds__(D4) void lru_phase3(const float4* __restrict__ x,
                                                 const float* __restrict__ W,
                                                 const float4* __restrict__ C,
                                                 float4* __restrict__ out) {
    const int d4 = threadIdx.x;
    const int k  = blockIdx.x;
    const int b  = blockIdx.y;
    const int d  = d4 * 4;

    float a0, a1, a2, a3, b0, b1, b2, b3;
    coeffs(W, d, a0, a1, a2, a3, b0, b1, b2, b3);

    float4 c = C[((size_t)b * KK + k) * D4 + d4];
    float h0 = c.x, h1 = c.y, h2 = c.z, h3 = c.w;

    const size_t base = ((size_t)b * TT + (size_t)k * LL) * D4 + d4;
    const float4* xp = x + base;
    float4* op = out + base;
#pragma unroll 8
    for (int i = 0; i < LL; ++i) {
        float4 v = xp[(size_t)i * D4];
        h0 = a0 * h0 + b0 * v.x;
        h1 = a1 * h1 + b1 * v.y;
        h2 = a2 * h2 + b2 * v.z;
        h3 = a3 * h3 + b3 * v.w;
        op[(size_t)i * D4] = make_float4(h0, h1, h2, h3);
    }
}

extern "C" void kernel_launch(void* const* d_in, const int* in_sizes, int n_in,
                              void* d_out, int out_size, void* d_ws, size_t ws_size,
                              hipStream_t stream) {
    const float4* x = (const float4*)d_in[0];   // [B,T,D] fp32
    const float*  W = (const float*)d_in[1];    // [D] fp32
    float4* out = (float4*)d_out;               // [B,T,D] fp32
    float4* E   = (float4*)d_ws;                // [B,KK,D] fp32 = 2 MiB

    dim3 grid(KK, BB);
    dim3 block(D4);
    lru_phase1<<<grid, block, 0, stream>>>(x, W, E);
    lru_phase2<<<dim3(BB), dim3(D4), 0, stream>>>(W, E);
    lru_phase3<<<grid, block, 0, stream>>>(x, W, E, out);
}